// Round 9
// baseline (319.045 us; speedup 1.0000x reference)
//
#include <hip/hip_runtime.h>
#include <math.h>

#define HW 25600
#define IMGW 160
#define CDIM 256
#define NB 4
#define NHEADS 8
#define SZB ((long)CDIM * HW)   // 6,553,600 elems

typedef __attribute__((ext_vector_type(8))) short short8v;
typedef __attribute__((ext_vector_type(4))) float f32x4;
typedef __attribute__((ext_vector_type(8))) unsigned short us8;

union FragU {
    us8 o;
    short8v s;
    unsigned u32[4];
};

__device__ inline unsigned short f2bf(float f) {
    unsigned u = __float_as_uint(f);
    return (unsigned short)((u + 0x7fffu + ((u >> 16) & 1u)) >> 16);
}
__device__ inline float bf2f(unsigned short h) {
    return __uint_as_float(((unsigned)h) << 16);
}

// ---------------------------------------------------------------------------
// all weights fp32 -> swizzled bf16, one dispatch.
// kv_w [512][256] -> wkv_s [8kt][512][32]; q_w [256][256] -> wq_s [8kt][256][32]
// slot(g2, co) = g2 ^ ((co>>1)&3).  grid(96)
// ---------------------------------------------------------------------------
__global__ __launch_bounds__(256) void cvtw_k(
    const float* __restrict__ kv_w, const float* __restrict__ q_w,
    unsigned short* __restrict__ wkv_s, unsigned short* __restrict__ wq_s)
{
    int idx = blockIdx.x * 256 + threadIdx.x;   // 0..24575
    int g2 = idx & 3;
    int kt = (idx >> 2) & 7;
    int co = idx >> 5;                          // 0..767
    const float* src;
    unsigned short* dst;
    int nco, co_l;
    if (co < 512) { src = kv_w; dst = wkv_s; nco = 512; co_l = co; }
    else          { src = q_w;  dst = wq_s;  nco = 256; co_l = co - 512; }
    src += (long)co_l * CDIM + kt * 32 + g2 * 8;
    us8 v;
#pragma unroll
    for (int u = 0; u < 8; ++u) v[u] = f2bf(src[u]);
    int slot = g2 ^ ((co_l >> 1) & 3);
    *(us8*)(dst + ((long)kt * nco + co_l) * 32 + slot * 8) = v;
}

// ---------------------------------------------------------------------------
// bf16 MFMA GEMM: out[b][co][n] = sum_k W[co][k] * X[k][n]
// W in swizzled [kt][nco][32] bf16 (glds staged).
// XF32=1: X fp32 [k][HW]; tile staged to LDS [32][133] fp32 (pad-133 ->
//         column reads are 2-way/free); B-frags via v_cvt_pk_bf16_f32.
// XF32=0: X swizzled bf16 [kt][HW][32] (glds staged, inverse-swz read).
// XCD-bijective block swizzle: each XCD owns contiguous n-panels with ALL
// their co-tiles -> X panel served from its L2 (kills the 2x HBM re-fetch).
// Requires (gridDim.x*gridDim.y) % 8 == 0.
// ---------------------------------------------------------------------------
template<int OUTF32, int XF32>
__global__ __launch_bounds__(256) void gemm2_k(
    const void* __restrict__ Xv, const unsigned short* __restrict__ WS,
    void* __restrict__ outp, long xbs, long wbs, long obs, int nco)
{
    __shared__ __align__(16) unsigned short Wl[128 * 32];
    __shared__ __align__(16) char XBuf[XF32 ? (32 * 133 * 4) : (128 * 32 * 2)];
    float* Xf = (float*)XBuf;
    unsigned short* Xl = (unsigned short*)XBuf;

    const int t  = threadIdx.x;
    const int l  = t & 63;
    const int wv = t >> 6;
    const int g  = l >> 4;
    const int ln = l & 15;

    // XCD-aware bijective swizzle (nwg % 8 == 0)
    const int NX = gridDim.x;
    const int orig = blockIdx.y * NX + blockIdx.x;
    const int chunkp = (NX * gridDim.y) >> 3;
    const int wgid = (orig & 7) * chunkp + (orig >> 3);
    const int co0 = (wgid % NX) * 128;
    const int n0  = (wgid / NX) * 128;

    const long b  = blockIdx.z;
    const unsigned short* Wb = WS + b * wbs;
    const int wr = wv >> 1, wc = wv & 1;

    f32x4 acc[4][4];
#pragma unroll
    for (int i = 0; i < 4; ++i)
#pragma unroll
        for (int j = 0; j < 4; ++j) acc[i][j] = (f32x4){0.f, 0.f, 0.f, 0.f};

    const int lrow = l >> 2;     // glds: lane covers row (instr*16 + lrow)
    const int lgrp = l & 3;      // 16B group

    for (int kt = 0; kt < 8; ++kt) {
        __syncthreads();
        // stage W tile [128co][32k] via glds (swizzled source, linear LDS)
#pragma unroll
        for (int ii = 0; ii < 2; ++ii) {
            int instr = wv * 2 + ii;
            int row = instr * 16 + lrow;
            const unsigned short* wsrc =
                Wb + ((long)kt * nco + co0 + row) * 32 + lgrp * 8;
            __builtin_amdgcn_global_load_lds(
                (const __attribute__((address_space(1))) void*)wsrc,
                (__attribute__((address_space(3))) void*)&Wl[instr * 512], 16, 0, 0);
        }
        if (XF32) {
            // stage X fp32 tile [32k][128n] -> Xf[32][133]
            const float* Xb = (const float*)Xv + b * xbs;
#pragma unroll
            for (int r = 0; r < 4; ++r) {
                int idx = r * 256 + t;
                int row = idx >> 5;          // 0..31
                int c4  = idx & 31;          // float4 col
                float4 v = *(const float4*)(Xb + (long)(kt * 32 + row) * HW
                                            + n0 + c4 * 4);
                *(float4*)&Xf[row * 133 + c4 * 4] = v;
            }
        } else {
            const unsigned short* Xb = (const unsigned short*)Xv + b * xbs;
#pragma unroll
            for (int ii = 0; ii < 2; ++ii) {
                int instr = wv * 2 + ii;
                int row = instr * 16 + lrow;
                const unsigned short* xsrc =
                    Xb + ((long)kt * HW + n0 + row) * 32 + lgrp * 8;
                __builtin_amdgcn_global_load_lds(
                    (const __attribute__((address_space(1))) void*)xsrc,
                    (__attribute__((address_space(3))) void*)&Xl[instr * 512], 16, 0, 0);
            }
        }
        __syncthreads();

        // A fragments (W): logical k = g*8+e, physical slot = g^((row>>1)&3)
        FragU A_[4], B_[4];
#pragma unroll
        for (int i = 0; i < 4; ++i) {
            int row = wr * 64 + i * 16 + ln;
            int slot = g ^ ((row >> 1) & 3);
            A_[i].o = *(const us8*)&Wl[row * 32 + slot * 8];
        }
        if (XF32) {
            // B fragments: column reads from fp32 LDS + cvt_pk (RNE)
#pragma unroll
            for (int j = 0; j < 4; ++j) {
                int n = wc * 64 + j * 16 + ln;
#pragma unroll
                for (int e2 = 0; e2 < 4; ++e2) {
                    float lo = Xf[(g * 8 + e2 * 2) * 133 + n];
                    float hi = Xf[(g * 8 + e2 * 2 + 1) * 133 + n];
                    unsigned r;
                    asm("v_cvt_pk_bf16_f32 %0, %1, %2"
                        : "=v"(r) : "v"(lo), "v"(hi));
                    B_[j].u32[e2] = r;
                }
            }
        } else {
#pragma unroll
            for (int j = 0; j < 4; ++j) {
                int row = wc * 64 + j * 16 + ln;
                int slot = g ^ ((row >> 1) & 3);
                B_[j].o = *(const us8*)&Xl[row * 32 + slot * 8];
            }
        }
#pragma unroll
        for (int i = 0; i < 4; ++i)
#pragma unroll
            for (int j = 0; j < 4; ++j)
                acc[i][j] = __builtin_amdgcn_mfma_f32_16x16x32_bf16(
                    A_[i].s, B_[j].s, acc[i][j], 0, 0, 0);
    }

    // epilogue: D layout col=lane&15, row=(lane>>4)*4+reg (HW-verified)
    if (OUTF32) {
        float* ob = (float*)outp + b * obs;
#pragma unroll
        for (int i = 0; i < 4; ++i)
#pragma unroll
            for (int j = 0; j < 4; ++j) {
                long ocol = n0 + wc * 64 + j * 16 + ln;
#pragma unroll
                for (int r = 0; r < 4; ++r) {
                    long orow = co0 + wr * 64 + i * 16 + g * 4 + r;
                    ob[orow * HW + ocol] = acc[i][j][r];
                }
            }
    } else {
        unsigned short* ob = (unsigned short*)outp + b * obs;
#pragma unroll
        for (int i = 0; i < 4; ++i)
#pragma unroll
            for (int j = 0; j < 4; ++j) {
                long ocol = n0 + wc * 64 + j * 16 + ln;
#pragma unroll
                for (int r = 0; r < 4; ++r) {
                    long orow = co0 + wr * 64 + i * 16 + g * 4 + r;
                    ob[orow * HW + ocol] = f2bf(acc[i][j][r]);
                }
            }
    }
}

// ---------------------------------------------------------------------------
// depthwise 3x3 bf16, normal output [c][HW].
// Tile: 8 output rows x 160 px x 8 ch. Halo 10/8 rows = 1.25x fetch.
// grid (20, 32, NB). bstride = input batch stride (elems).
// ---------------------------------------------------------------------------
__global__ __launch_bounds__(256) void dwK_k(
    const unsigned short* __restrict__ A, const float* __restrict__ w,
    unsigned short* __restrict__ out, long bstride)
{
    __shared__ unsigned short xsh[8][10][168];
    const int t = threadIdx.x;
    const int y0 = blockIdx.x * 8;
    const int c0 = blockIdx.y * 8;
    const long b = blockIdx.z;
    const unsigned short* Ab = A + b * bstride;

    for (int idx = t; idx < 1600; idx += 256) {
        int seg = idx % 20;
        int row = (idx / 20) % 10;
        int ch  = idx / 200;
        int yy  = y0 + row - 1;
        us8 v = (us8){0, 0, 0, 0, 0, 0, 0, 0};
        if (yy >= 0 && yy < IMGW)
            v = *(const us8*)(Ab + (long)(c0 + ch) * HW + yy * IMGW + seg * 8);
        *(us8*)&xsh[ch][row][seg * 8] = v;
    }
    __syncthreads();

    const int ch = t >> 5;
    const int rem = t & 31;
    const int ro = rem >> 2;
    const int xq = rem & 3;
    float wreg[9];
#pragma unroll
    for (int u = 0; u < 9; ++u) wreg[u] = w[(c0 + ch) * 9 + u];
    unsigned short* ob = out + b * SZB + (long)(c0 + ch) * HW + (y0 + ro) * IMGW;

#pragma unroll
    for (int xs = 0; xs < 5; ++xs) {
        int x = xq * 8 + xs * 32;
        float s[8];
#pragma unroll
        for (int p = 0; p < 8; ++p) s[p] = 0.f;
#pragma unroll
        for (int dy = 0; dy < 3; ++dy) {
            const unsigned short* rp = &xsh[ch][ro + dy][0];
            float r[10];
            r[0] = (x > 0) ? bf2f(rp[x - 1]) : 0.f;
            us8 mid = *(const us8*)&rp[x];
#pragma unroll
            for (int u = 0; u < 8; ++u) r[1 + u] = bf2f(mid[u]);
            r[9] = (x + 8 < IMGW) ? bf2f(rp[x + 8]) : 0.f;
            float w0 = wreg[dy * 3], w1 = wreg[dy * 3 + 1], w2 = wreg[dy * 3 + 2];
#pragma unroll
            for (int p = 0; p < 8; ++p)
                s[p] = fmaf(w0, r[p], fmaf(w1, r[p + 1], fmaf(w2, r[p + 2], s[p])));
        }
        us8 o;
#pragma unroll
        for (int p = 0; p < 8; ++p) o[p] = f2bf(s[p]);
        *(us8*)(ob + x) = o;
    }
}

// ---------------------------------------------------------------------------
// depthwise 3x3 bf16, transposed+swizzled output [kt][HW][32] (for V).
// Tile: 4 output rows x 160 px x 16 ch. grid (40, 16, NB).
// ---------------------------------------------------------------------------
__global__ __launch_bounds__(256) void dwV_k(
    const unsigned short* __restrict__ A, const float* __restrict__ w,
    unsigned short* __restrict__ out, long bstride)
{
    __shared__ unsigned short xsh[16][6][168];
    __shared__ unsigned short osh[640][17];
    const int t = threadIdx.x;
    const int y0 = blockIdx.x * 4;
    const int c0 = blockIdx.y * 16;
    const long b = blockIdx.z;
    const unsigned short* Ab = A + b * bstride;

    for (int idx = t; idx < 1920; idx += 256) {
        int seg = idx % 20;
        int row = (idx / 20) % 6;
        int ch  = idx / 120;
        int yy  = y0 + row - 1;
        us8 v = (us8){0, 0, 0, 0, 0, 0, 0, 0};
        if (yy >= 0 && yy < IMGW)
            v = *(const us8*)(Ab + (long)(c0 + ch) * HW + yy * IMGW + seg * 8);
        *(us8*)&xsh[ch][row][seg * 8] = v;
    }
    __syncthreads();

    {
        const int ch = t >> 4;
        const int rem = t & 15;
        const int ro = rem >> 2;
        const int xq = rem & 3;
        float wreg[9];
#pragma unroll
        for (int u = 0; u < 9; ++u) wreg[u] = w[(c0 + ch) * 9 + u];
#pragma unroll
        for (int xs = 0; xs < 5; ++xs) {
            int x = xq * 8 + xs * 32;
            float s[8];
#pragma unroll
            for (int p = 0; p < 8; ++p) s[p] = 0.f;
#pragma unroll
            for (int dy = 0; dy < 3; ++dy) {
                const unsigned short* rp = &xsh[ch][ro + dy][0];
                float r[10];
                r[0] = (x > 0) ? bf2f(rp[x - 1]) : 0.f;
                us8 mid = *(const us8*)&rp[x];
#pragma unroll
                for (int u = 0; u < 8; ++u) r[1 + u] = bf2f(mid[u]);
                r[9] = (x + 8 < IMGW) ? bf2f(rp[x + 8]) : 0.f;
                float w0 = wreg[dy * 3], w1 = wreg[dy * 3 + 1], w2 = wreg[dy * 3 + 2];
#pragma unroll
                for (int p = 0; p < 8; ++p)
                    s[p] = fmaf(w0, r[p], fmaf(w1, r[p + 1], fmaf(w2, r[p + 2], s[p])));
            }
            int nl = ro * IMGW + x;
#pragma unroll
            for (int p = 0; p < 8; ++p) osh[nl + p][ch] = f2bf(s[p]);
        }
    }
    __syncthreads();

    for (int idx = t; idx < 1280; idx += 256) {
        int nl = idx >> 1;
        int c8 = (idx & 1) * 8;
        us8 o;
#pragma unroll
        for (int u = 0; u < 8; ++u) o[u] = osh[nl][c8 + u];
        int n  = y0 * IMGW + nl;
        int cg = c0 + c8;
        int kt = cg >> 5;
        int g2 = (cg >> 3) & 3;
        int slot = g2 ^ ((n >> 1) & 3);
        *(us8*)(out + b * SZB + ((long)kt * HW + n) * 32 + slot * 8) = o;
    }
}

// ---------------------------------------------------------------------------
// gram via MFMA, direct global us8 frag loads (same k-slot map both operands).
// grid (8 chunks, 8 heads, NB)
// ---------------------------------------------------------------------------
__global__ __launch_bounds__(256) void gram_k(
    const unsigned short* __restrict__ q, const unsigned short* __restrict__ k,
    float* __restrict__ part_qk, float* __restrict__ part_sq_q,
    float* __restrict__ part_sq_k)
{
    __shared__ float Sred[4 * 1024];
    __shared__ float sqq_l[4][32];
    __shared__ float sqk_l[4][32];
    const int t  = threadIdx.x;
    const int l  = t & 63;
    const int wv = t >> 6;
    const int g  = l >> 4;
    const int ln = l & 15;
    const int chunk = blockIdx.x;
    const int h = blockIdx.y;
    const int b = blockIdx.z;

    f32x4 accS[2][2], accQ[2], accK[2];
#pragma unroll
    for (int i = 0; i < 2; ++i) {
        accQ[i] = (f32x4){0, 0, 0, 0};
        accK[i] = (f32x4){0, 0, 0, 0};
#pragma unroll
        for (int j = 0; j < 2; ++j) accS[i][j] = (f32x4){0, 0, 0, 0};
    }

    const unsigned short* qb = q + (long)b * SZB + (long)(h * 32) * HW;
    const unsigned short* kb = k + (long)b * SZB + (long)(h * 32) * HW;
    long nb = (long)chunk * 3200 + wv * 800;
    for (int s = 0; s < 25; ++s, nb += 32) {
        FragU aq[2], bk[2];
#pragma unroll
        for (int i = 0; i < 2; ++i)
            aq[i].o = *(const us8*)(qb + (long)(i * 16 + ln) * HW + nb + g * 8);
#pragma unroll
        for (int j = 0; j < 2; ++j)
            bk[j].o = *(const us8*)(kb + (long)(j * 16 + ln) * HW + nb + g * 8);
#pragma unroll
        for (int i = 0; i < 2; ++i)
#pragma unroll
            for (int j = 0; j < 2; ++j)
                accS[i][j] = __builtin_amdgcn_mfma_f32_16x16x32_bf16(
                    aq[i].s, bk[j].s, accS[i][j], 0, 0, 0);
#pragma unroll
        for (int i = 0; i < 2; ++i) {
            accQ[i] = __builtin_amdgcn_mfma_f32_16x16x32_bf16(
                aq[i].s, aq[i].s, accQ[i], 0, 0, 0);
            accK[i] = __builtin_amdgcn_mfma_f32_16x16x32_bf16(
                bk[i].s, bk[i].s, accK[i], 0, 0, 0);
        }
    }
#pragma unroll
    for (int i = 0; i < 2; ++i)
#pragma unroll
        for (int j = 0; j < 2; ++j)
#pragma unroll
            for (int r = 0; r < 4; ++r) {
                int row = i * 16 + g * 4 + r;
                int col = j * 16 + ln;
                Sred[wv * 1024 + row * 32 + col] = accS[i][j][r];
            }
#pragma unroll
    for (int i = 0; i < 2; ++i)
#pragma unroll
        for (int r = 0; r < 4; ++r)
            if (ln == g * 4 + r) {
                sqq_l[wv][i * 16 + g * 4 + r] = accQ[i][r];
                sqk_l[wv][i * 16 + g * 4 + r] = accK[i][r];
            }
    __syncthreads();
    const long pb = ((long)(b * NHEADS + h) * 8 + chunk);
#pragma unroll
    for (int e0 = 0; e0 < 4; ++e0) {
        int e = e0 * 256 + t;
        float v = Sred[e] + Sred[1024 + e] + Sred[2048 + e] + Sred[3072 + e];
        part_qk[pb * 1024 + e] = v;
    }
    if (t < 32)
        part_sq_q[pb * 32 + t] = sqq_l[0][t] + sqq_l[1][t] + sqq_l[2][t] + sqq_l[3][t];
    else if (t < 64) {
        int j = t - 32;
        part_sq_k[pb * 32 + j] = sqk_l[0][j] + sqk_l[1][j] + sqk_l[2][j] + sqk_l[3][j];
    }
}

// ---------------------------------------------------------------------------
// reduce -> normalize -> softmax -> W_eff = proj_w @ blockdiag(attn),
// stored in swizzled [b][kt=h][256][32] layout. grid 32 = (b,h)
// ---------------------------------------------------------------------------
__global__ __launch_bounds__(256) void attn_weff_k(
    const float* __restrict__ part_qk, const float* __restrict__ part_sq_q,
    const float* __restrict__ part_sq_k, const float* __restrict__ proj_w,
    const float* __restrict__ temp, unsigned short* __restrict__ weff_s)
{
    __shared__ float at[32 * 33];
    __shared__ float nq[32], nk[32];
    int bh = blockIdx.x;
    int b = bh >> 3, h = bh & 7;
    int t = threadIdx.x;
    long pb0 = (long)bh * 8;
    float4 s = make_float4(0, 0, 0, 0);
    for (int c = 0; c < 8; ++c) {
        float4 v = *(const float4*)(part_qk + (pb0 + c) * 1024 + t * 4);
        s.x += v.x; s.y += v.y; s.z += v.z; s.w += v.w;
    }
    if (t < 32) {
        float a = 0;
        for (int c = 0; c < 8; ++c) a += part_sq_q[(pb0 + c) * 32 + t];
        nq[t] = fmaxf(sqrtf(a), 1e-12f);
    } else if (t < 64) {
        int j = t - 32;
        float a = 0;
        for (int c = 0; c < 8; ++c) a += part_sq_k[(pb0 + c) * 32 + j];
        nk[j] = fmaxf(sqrtf(a), 1e-12f);
    }
    __syncthreads();
    float tp = temp[h];
    int ci = t >> 3, cj0 = (t & 7) * 4;
    at[ci * 33 + cj0 + 0] = s.x / (nq[ci] * nk[cj0 + 0]) * tp;
    at[ci * 33 + cj0 + 1] = s.y / (nq[ci] * nk[cj0 + 1]) * tp;
    at[ci * 33 + cj0 + 2] = s.z / (nq[ci] * nk[cj0 + 2]) * tp;
    at[ci * 33 + cj0 + 3] = s.w / (nq[ci] * nk[cj0 + 3]) * tp;
    __syncthreads();
    if (t < 32) {
        float m = -1e30f;
        for (int j = 0; j < 32; ++j) m = fmaxf(m, at[t * 33 + j]);
        float ss = 0;
        for (int j = 0; j < 32; ++j) {
            float e = expf(at[t * 33 + j] - m);
            at[t * 33 + j] = e;
            ss += e;
        }
        float inv = 1.f / ss;
        for (int j = 0; j < 32; ++j) at[t * 33 + j] *= inv;
    }
    __syncthreads();
    int co = t;
    float pw[32];
#pragma unroll
    for (int i2 = 0; i2 < 32; ++i2) pw[i2] = proj_w[(long)co * CDIM + h * 32 + i2];
    unsigned short* wb = weff_s + (long)b * 65536 + (long)h * (256 * 32) + co * 32;
    int swz = (co >> 1) & 3;
    for (int j = 0; j < 32; ++j) {
        float a = 0;
#pragma unroll
        for (int i2 = 0; i2 < 32; ++i2) a = fmaf(pw[i2], at[i2 * 33 + j], a);
        wb[((j >> 3) ^ swz) * 8 + (j & 7)] = f2bf(a);
    }
}

// ---------------------------------------------------------------------------
extern "C" void kernel_launch(void* const* d_in, const int* in_sizes, int n_in,
                              void* d_out, int out_size, void* d_ws, size_t ws_size,
                              hipStream_t stream)
{
    const float* low    = (const float*)d_in[0];
    const float* high   = (const float*)d_in[1];
    const float* q_w    = (const float*)d_in[2];
    const float* q_dw   = (const float*)d_in[3];
    const float* kv_w   = (const float*)d_in[4];
    const float* kv_dw  = (const float*)d_in[5];
    const float* proj_w = (const float*)d_in[6];
    const float* temp   = (const float*)d_in[7];
    float* out = (float*)d_out;

    // workspace (bf16 elems)
    unsigned short* usws = (unsigned short*)d_ws;
    unsigned short* Areg = usws;                  // [4][512][HW]   8*SZB
    unsigned short* VT   = Areg + 8 * SZB;        // [4][8][HW][32] 4*SZB
    unsigned short* wkv_s = VT + 4 * SZB;         // [8][512][32]
    unsigned short* wq_s  = wkv_s + 131072;       // [8][256][32]
    unsigned short* weff_s = wq_s + 65536;        // [4][8][256][32]
    float* part_qk   = (float*)(weff_s + 4L * 65536);
    float* part_sq_q = part_qk + 32L * 8 * 1024;
    float* part_sq_k = part_sq_q + 32L * 8 * 32;
    float* endp      = part_sq_k + 32L * 8 * 32;
    if (ws_size < (size_t)((char*)endp - (char*)d_ws)) return;

    // d_out as scratch: K_all then Q_all (bf16), consumed before final write
    unsigned short* K_all = (unsigned short*)d_out;           // [4][256][HW]
    unsigned short* Q_all = K_all + 4 * SZB;                  // [4][256][HW]

    dim3 blk(256);

    // all weights -> swizzled bf16 (1 dispatch)
    cvtw_k<<<dim3(96), blk, 0, stream>>>(kv_w, q_w, wkv_s, wq_s);

    // kv chain: fused K+V GEMM straight from fp32 low
    gemm2_k<0, 1><<<dim3(4, 200, NB), blk, 0, stream>>>(
        low, wkv_s, Areg, SZB, 0, 2 * SZB, 512);
    dwK_k<<<dim3(20, 32, NB), blk, 0, stream>>>(Areg, kv_dw, K_all, 2 * SZB);
    dwV_k<<<dim3(40, 16, NB), blk, 0, stream>>>(Areg + 256L * HW,
                                                kv_dw + 256 * 9, VT, 2 * SZB);

    // q chain (reuses Areg rows 0..255, stride 2*SZB)
    gemm2_k<0, 1><<<dim3(2, 200, NB), blk, 0, stream>>>(
        high, wq_s, Areg, SZB, 0, 2 * SZB, 256);
    dwK_k<<<dim3(20, 32, NB), blk, 0, stream>>>(Areg, q_dw, Q_all, 2 * SZB);

    // gram + softmax + W_eff
    gram_k<<<dim3(8, NHEADS, NB), blk, 0, stream>>>(Q_all, K_all, part_qk,
                                                    part_sq_q, part_sq_k);
    attn_weff_k<<<dim3(32), blk, 0, stream>>>(
        part_qk, part_sq_q, part_sq_k, proj_w, temp, weff_s);

    // out[b] = W_eff[b] @ v[b]
    gemm2_k<1, 0><<<dim3(2, 200, NB), blk, 0, stream>>>(VT, weff_s, out,
                                                        SZB, 65536, SZB, 256);
}

// Round 10
// 308.211 us; speedup vs baseline: 1.0351x; 1.0351x over previous
//
#include <hip/hip_runtime.h>
#include <math.h>

#define HW 25600
#define IMGW 160
#define CDIM 256
#define NB 4
#define NHEADS 8
#define SZB ((long)CDIM * HW)   // 6,553,600 elems

typedef __attribute__((ext_vector_type(8))) short short8v;
typedef __attribute__((ext_vector_type(4))) float f32x4;
typedef __attribute__((ext_vector_type(8))) unsigned short us8;

union FragU {
    us8 o;
    short8v s;
    unsigned u32[4];
};

__device__ inline unsigned short f2bf(float f) {
    unsigned u = __float_as_uint(f);
    return (unsigned short)((u + 0x7fffu + ((u >> 16) & 1u)) >> 16);
}
__device__ inline float bf2f(unsigned short h) {
    return __uint_as_float(((unsigned)h) << 16);
}

// ---------------------------------------------------------------------------
// all weights fp32 -> swizzled bf16, one dispatch.
// kv_w [512][256] -> wkv_s [8kt][512][32]; q_w [256][256] -> wq_s [8kt][256][32]
// slot(g2, co) = g2 ^ ((co>>1)&3).  grid(96)
// ---------------------------------------------------------------------------
__global__ __launch_bounds__(256) void cvtw_k(
    const float* __restrict__ kv_w, const float* __restrict__ q_w,
    unsigned short* __restrict__ wkv_s, unsigned short* __restrict__ wq_s)
{
    int idx = blockIdx.x * 256 + threadIdx.x;   // 0..24575
    int g2 = idx & 3;
    int kt = (idx >> 2) & 7;
    int co = idx >> 5;                          // 0..767
    const float* src;
    unsigned short* dst;
    int nco, co_l;
    if (co < 512) { src = kv_w; dst = wkv_s; nco = 512; co_l = co; }
    else          { src = q_w;  dst = wq_s;  nco = 256; co_l = co - 512; }
    src += (long)co_l * CDIM + kt * 32 + g2 * 8;
    us8 v;
#pragma unroll
    for (int u = 0; u < 8; ++u) v[u] = f2bf(src[u]);
    int slot = g2 ^ ((co_l >> 1) & 3);
    *(us8*)(dst + ((long)kt * nco + co_l) * 32 + slot * 8) = v;
}

// ---------------------------------------------------------------------------
// bf16 MFMA GEMM: out[b][co][n] = sum_k W[co][k] * X[k][n]
// W in swizzled [kt][nco][32] bf16 (glds staged).
// XF32=1: X fp32 [k][HW]; per-thread k-strip loads (coalesced 256B wave
//         reads), register cvt_pk -> bf16, ds_write_b128 into [128n][40]
//         LDS tile; B-frags are clean ds_read_b128 (m92-pad pattern).
// XF32=0: X swizzled bf16 [kt][HW][32] (glds staged, inverse-swz read).
// XCD-bijective block swizzle keeps each X panel on one XCD's L2.
// Requires (gridDim.x*gridDim.y) % 8 == 0.
// ---------------------------------------------------------------------------
template<int OUTF32, int XF32>
__global__ __launch_bounds__(256) void gemm2_k(
    const void* __restrict__ Xv, const unsigned short* __restrict__ WS,
    void* __restrict__ outp, long xbs, long wbs, long obs, int nco)
{
    __shared__ __align__(16) unsigned short Wl[128 * 32];
    __shared__ __align__(16) char XBuf[XF32 ? (128 * 40 * 2) : (128 * 32 * 2)];
    unsigned short* Xl = (unsigned short*)XBuf;

    const int t  = threadIdx.x;
    const int l  = t & 63;
    const int wv = t >> 6;
    const int g  = l >> 4;
    const int ln = l & 15;

    // XCD-aware bijective swizzle (nwg % 8 == 0)
    const int NX = gridDim.x;
    const int orig = blockIdx.y * NX + blockIdx.x;
    const int chunkp = (NX * gridDim.y) >> 3;
    const int wgid = (orig & 7) * chunkp + (orig >> 3);
    const int co0 = (wgid % NX) * 128;
    const int n0  = (wgid / NX) * 128;

    const long b  = blockIdx.z;
    const unsigned short* Wb = WS + b * wbs;
    const int wr = wv >> 1, wc = wv & 1;

    f32x4 acc[4][4];
#pragma unroll
    for (int i = 0; i < 4; ++i)
#pragma unroll
        for (int j = 0; j < 4; ++j) acc[i][j] = (f32x4){0.f, 0.f, 0.f, 0.f};

    const int lrow = l >> 2;     // glds: lane covers row (instr*16 + lrow)
    const int lgrp = l & 3;      // 16B group
    const int n_l = t & 127;     // XF32 staging: n within tile
    const int sb  = (t >> 7) * 2; // XF32 staging: strip base (k-groups of 8)

    for (int kt = 0; kt < 8; ++kt) {
        __syncthreads();
        // stage W tile [128co][32k] via glds (swizzled source, linear LDS)
#pragma unroll
        for (int ii = 0; ii < 2; ++ii) {
            int instr = wv * 2 + ii;
            int row = instr * 16 + lrow;
            const unsigned short* wsrc =
                Wb + ((long)kt * nco + co0 + row) * 32 + lgrp * 8;
            __builtin_amdgcn_global_load_lds(
                (const __attribute__((address_space(1))) void*)wsrc,
                (__attribute__((address_space(3))) void*)&Wl[instr * 512], 16, 0, 0);
        }
        if (XF32) {
            // stage X fp32 -> bf16 in registers -> [128n][40] LDS tile
            const float* Xb = (const float*)Xv + b * xbs;
#pragma unroll
            for (int si = 0; si < 2; ++si) {
                int k0 = (sb + si) * 8;
                float f[8];
#pragma unroll
                for (int u = 0; u < 8; ++u)
                    f[u] = Xb[(long)(kt * 32 + k0 + u) * HW + n0 + n_l];
                FragU cv;
#pragma unroll
                for (int e2 = 0; e2 < 4; ++e2) {
                    unsigned r;
                    asm("v_cvt_pk_bf16_f32 %0, %1, %2"
                        : "=v"(r) : "v"(f[e2 * 2]), "v"(f[e2 * 2 + 1]));
                    cv.u32[e2] = r;
                }
                *(us8*)&Xl[n_l * 40 + k0] = cv.o;
            }
        } else {
            const unsigned short* Xb = (const unsigned short*)Xv + b * xbs;
#pragma unroll
            for (int ii = 0; ii < 2; ++ii) {
                int instr = wv * 2 + ii;
                int row = instr * 16 + lrow;
                const unsigned short* xsrc =
                    Xb + ((long)kt * HW + n0 + row) * 32 + lgrp * 8;
                __builtin_amdgcn_global_load_lds(
                    (const __attribute__((address_space(1))) void*)xsrc,
                    (__attribute__((address_space(3))) void*)&Xl[instr * 512], 16, 0, 0);
            }
        }
        __syncthreads();

        // A fragments (W): logical k = g*8+e, physical slot = g^((row>>1)&3)
        FragU A_[4], B_[4];
#pragma unroll
        for (int i = 0; i < 4; ++i) {
            int row = wr * 64 + i * 16 + ln;
            int slot = g ^ ((row >> 1) & 3);
            A_[i].o = *(const us8*)&Wl[row * 32 + slot * 8];
        }
        if (XF32) {
            // B fragments: contiguous us8 from pad-40 rows (k = g*8..g*8+7)
#pragma unroll
            for (int j = 0; j < 4; ++j) {
                int row = wc * 64 + j * 16 + ln;
                B_[j].o = *(const us8*)&Xl[row * 40 + g * 8];
            }
        } else {
#pragma unroll
            for (int j = 0; j < 4; ++j) {
                int row = wc * 64 + j * 16 + ln;
                int slot = g ^ ((row >> 1) & 3);
                B_[j].o = *(const us8*)&Xl[row * 32 + slot * 8];
            }
        }
#pragma unroll
        for (int i = 0; i < 4; ++i)
#pragma unroll
            for (int j = 0; j < 4; ++j)
                acc[i][j] = __builtin_amdgcn_mfma_f32_16x16x32_bf16(
                    A_[i].s, B_[j].s, acc[i][j], 0, 0, 0);
    }

    // epilogue: D layout col=lane&15, row=(lane>>4)*4+reg (HW-verified)
    if (OUTF32) {
        float* ob = (float*)outp + b * obs;
#pragma unroll
        for (int i = 0; i < 4; ++i)
#pragma unroll
            for (int j = 0; j < 4; ++j) {
                long ocol = n0 + wc * 64 + j * 16 + ln;
#pragma unroll
                for (int r = 0; r < 4; ++r) {
                    long orow = co0 + wr * 64 + i * 16 + g * 4 + r;
                    ob[orow * HW + ocol] = acc[i][j][r];
                }
            }
    } else {
        unsigned short* ob = (unsigned short*)outp + b * obs;
#pragma unroll
        for (int i = 0; i < 4; ++i)
#pragma unroll
            for (int j = 0; j < 4; ++j) {
                long ocol = n0 + wc * 64 + j * 16 + ln;
#pragma unroll
                for (int r = 0; r < 4; ++r) {
                    long orow = co0 + wr * 64 + i * 16 + g * 4 + r;
                    ob[orow * HW + ocol] = f2bf(acc[i][j][r]);
                }
            }
    }
}

// ---------------------------------------------------------------------------
// depthwise 3x3 bf16, normal output [c][HW].
// Tile: 8 output rows x 160 px x 8 ch. Halo 10/8 rows = 1.25x fetch.
// grid (20, 32, NB). bstride = input batch stride (elems).
// ---------------------------------------------------------------------------
__global__ __launch_bounds__(256) void dwK_k(
    const unsigned short* __restrict__ A, const float* __restrict__ w,
    unsigned short* __restrict__ out, long bstride)
{
    __shared__ unsigned short xsh[8][10][168];
    const int t = threadIdx.x;
    const int y0 = blockIdx.x * 8;
    const int c0 = blockIdx.y * 8;
    const long b = blockIdx.z;
    const unsigned short* Ab = A + b * bstride;

    for (int idx = t; idx < 1600; idx += 256) {
        int seg = idx % 20;
        int row = (idx / 20) % 10;
        int ch  = idx / 200;
        int yy  = y0 + row - 1;
        us8 v = (us8){0, 0, 0, 0, 0, 0, 0, 0};
        if (yy >= 0 && yy < IMGW)
            v = *(const us8*)(Ab + (long)(c0 + ch) * HW + yy * IMGW + seg * 8);
        *(us8*)&xsh[ch][row][seg * 8] = v;
    }
    __syncthreads();

    const int ch = t >> 5;
    const int rem = t & 31;
    const int ro = rem >> 2;
    const int xq = rem & 3;
    float wreg[9];
#pragma unroll
    for (int u = 0; u < 9; ++u) wreg[u] = w[(c0 + ch) * 9 + u];
    unsigned short* ob = out + b * SZB + (long)(c0 + ch) * HW + (y0 + ro) * IMGW;

#pragma unroll
    for (int xs = 0; xs < 5; ++xs) {
        int x = xq * 8 + xs * 32;
        float s[8];
#pragma unroll
        for (int p = 0; p < 8; ++p) s[p] = 0.f;
#pragma unroll
        for (int dy = 0; dy < 3; ++dy) {
            const unsigned short* rp = &xsh[ch][ro + dy][0];
            float r[10];
            r[0] = (x > 0) ? bf2f(rp[x - 1]) : 0.f;
            us8 mid = *(const us8*)&rp[x];
#pragma unroll
            for (int u = 0; u < 8; ++u) r[1 + u] = bf2f(mid[u]);
            r[9] = (x + 8 < IMGW) ? bf2f(rp[x + 8]) : 0.f;
            float w0 = wreg[dy * 3], w1 = wreg[dy * 3 + 1], w2 = wreg[dy * 3 + 2];
#pragma unroll
            for (int p = 0; p < 8; ++p)
                s[p] = fmaf(w0, r[p], fmaf(w1, r[p + 1], fmaf(w2, r[p + 2], s[p])));
        }
        us8 o;
#pragma unroll
        for (int p = 0; p < 8; ++p) o[p] = f2bf(s[p]);
        *(us8*)(ob + x) = o;
    }
}

// ---------------------------------------------------------------------------
// depthwise 3x3 bf16, transposed+swizzled output [kt][HW][32] (for V).
// Tile: 4 output rows x 160 px x 16 ch. grid (40, 16, NB).
// ---------------------------------------------------------------------------
__global__ __launch_bounds__(256) void dwV_k(
    const unsigned short* __restrict__ A, const float* __restrict__ w,
    unsigned short* __restrict__ out, long bstride)
{
    __shared__ unsigned short xsh[16][6][168];
    __shared__ unsigned short osh[640][17];
    const int t = threadIdx.x;
    const int y0 = blockIdx.x * 4;
    const int c0 = blockIdx.y * 16;
    const long b = blockIdx.z;
    const unsigned short* Ab = A + b * bstride;

    for (int idx = t; idx < 1920; idx += 256) {
        int seg = idx % 20;
        int row = (idx / 20) % 6;
        int ch  = idx / 120;
        int yy  = y0 + row - 1;
        us8 v = (us8){0, 0, 0, 0, 0, 0, 0, 0};
        if (yy >= 0 && yy < IMGW)
            v = *(const us8*)(Ab + (long)(c0 + ch) * HW + yy * IMGW + seg * 8);
        *(us8*)&xsh[ch][row][seg * 8] = v;
    }
    __syncthreads();

    {
        const int ch = t >> 4;
        const int rem = t & 15;
        const int ro = rem >> 2;
        const int xq = rem & 3;
        float wreg[9];
#pragma unroll
        for (int u = 0; u < 9; ++u) wreg[u] = w[(c0 + ch) * 9 + u];
#pragma unroll
        for (int xs = 0; xs < 5; ++xs) {
            int x = xq * 8 + xs * 32;
            float s[8];
#pragma unroll
            for (int p = 0; p < 8; ++p) s[p] = 0.f;
#pragma unroll
            for (int dy = 0; dy < 3; ++dy) {
                const unsigned short* rp = &xsh[ch][ro + dy][0];
                float r[10];
                r[0] = (x > 0) ? bf2f(rp[x - 1]) : 0.f;
                us8 mid = *(const us8*)&rp[x];
#pragma unroll
                for (int u = 0; u < 8; ++u) r[1 + u] = bf2f(mid[u]);
                r[9] = (x + 8 < IMGW) ? bf2f(rp[x + 8]) : 0.f;
                float w0 = wreg[dy * 3], w1 = wreg[dy * 3 + 1], w2 = wreg[dy * 3 + 2];
#pragma unroll
                for (int p = 0; p < 8; ++p)
                    s[p] = fmaf(w0, r[p], fmaf(w1, r[p + 1], fmaf(w2, r[p + 2], s[p])));
            }
            int nl = ro * IMGW + x;
#pragma unroll
            for (int p = 0; p < 8; ++p) osh[nl + p][ch] = f2bf(s[p]);
        }
    }
    __syncthreads();

    for (int idx = t; idx < 1280; idx += 256) {
        int nl = idx >> 1;
        int c8 = (idx & 1) * 8;
        us8 o;
#pragma unroll
        for (int u = 0; u < 8; ++u) o[u] = osh[nl][c8 + u];
        int n  = y0 * IMGW + nl;
        int cg = c0 + c8;
        int kt = cg >> 5;
        int g2 = (cg >> 3) & 3;
        int slot = g2 ^ ((n >> 1) & 3);
        *(us8*)(out + b * SZB + ((long)kt * HW + n) * 32 + slot * 8) = o;
    }
}

// ---------------------------------------------------------------------------
// gram via MFMA, direct global us8 frag loads (same k-slot map both operands).
// grid (8 chunks, 8 heads, NB)
// ---------------------------------------------------------------------------
__global__ __launch_bounds__(256) void gram_k(
    const unsigned short* __restrict__ q, const unsigned short* __restrict__ k,
    float* __restrict__ part_qk, float* __restrict__ part_sq_q,
    float* __restrict__ part_sq_k)
{
    __shared__ float Sred[4 * 1024];
    __shared__ float sqq_l[4][32];
    __shared__ float sqk_l[4][32];
    const int t  = threadIdx.x;
    const int l  = t & 63;
    const int wv = t >> 6;
    const int g  = l >> 4;
    const int ln = l & 15;
    const int chunk = blockIdx.x;
    const int h = blockIdx.y;
    const int b = blockIdx.z;

    f32x4 accS[2][2], accQ[2], accK[2];
#pragma unroll
    for (int i = 0; i < 2; ++i) {
        accQ[i] = (f32x4){0, 0, 0, 0};
        accK[i] = (f32x4){0, 0, 0, 0};
#pragma unroll
        for (int j = 0; j < 2; ++j) accS[i][j] = (f32x4){0, 0, 0, 0};
    }

    const unsigned short* qb = q + (long)b * SZB + (long)(h * 32) * HW;
    const unsigned short* kb = k + (long)b * SZB + (long)(h * 32) * HW;
    long nb = (long)chunk * 3200 + wv * 800;
    for (int s = 0; s < 25; ++s, nb += 32) {
        FragU aq[2], bk[2];
#pragma unroll
        for (int i = 0; i < 2; ++i)
            aq[i].o = *(const us8*)(qb + (long)(i * 16 + ln) * HW + nb + g * 8);
#pragma unroll
        for (int j = 0; j < 2; ++j)
            bk[j].o = *(const us8*)(kb + (long)(j * 16 + ln) * HW + nb + g * 8);
#pragma unroll
        for (int i = 0; i < 2; ++i)
#pragma unroll
            for (int j = 0; j < 2; ++j)
                accS[i][j] = __builtin_amdgcn_mfma_f32_16x16x32_bf16(
                    aq[i].s, bk[j].s, accS[i][j], 0, 0, 0);
#pragma unroll
        for (int i = 0; i < 2; ++i) {
            accQ[i] = __builtin_amdgcn_mfma_f32_16x16x32_bf16(
                aq[i].s, aq[i].s, accQ[i], 0, 0, 0);
            accK[i] = __builtin_amdgcn_mfma_f32_16x16x32_bf16(
                bk[i].s, bk[i].s, accK[i], 0, 0, 0);
        }
    }
#pragma unroll
    for (int i = 0; i < 2; ++i)
#pragma unroll
        for (int j = 0; j < 2; ++j)
#pragma unroll
            for (int r = 0; r < 4; ++r) {
                int row = i * 16 + g * 4 + r;
                int col = j * 16 + ln;
                Sred[wv * 1024 + row * 32 + col] = accS[i][j][r];
            }
#pragma unroll
    for (int i = 0; i < 2; ++i)
#pragma unroll
        for (int r = 0; r < 4; ++r)
            if (ln == g * 4 + r) {
                sqq_l[wv][i * 16 + g * 4 + r] = accQ[i][r];
                sqk_l[wv][i * 16 + g * 4 + r] = accK[i][r];
            }
    __syncthreads();
    const long pb = ((long)(b * NHEADS + h) * 8 + chunk);
#pragma unroll
    for (int e0 = 0; e0 < 4; ++e0) {
        int e = e0 * 256 + t;
        float v = Sred[e] + Sred[1024 + e] + Sred[2048 + e] + Sred[3072 + e];
        part_qk[pb * 1024 + e] = v;
    }
    if (t < 32)
        part_sq_q[pb * 32 + t] = sqq_l[0][t] + sqq_l[1][t] + sqq_l[2][t] + sqq_l[3][t];
    else if (t < 64) {
        int j = t - 32;
        part_sq_k[pb * 32 + j] = sqk_l[0][j] + sqk_l[1][j] + sqk_l[2][j] + sqk_l[3][j];
    }
}

// ---------------------------------------------------------------------------
// reduce -> normalize -> softmax -> W_eff = proj_w @ blockdiag(attn),
// stored in swizzled [b][kt=h][256][32] layout. grid 32 = (b,h)
// ---------------------------------------------------------------------------
__global__ __launch_bounds__(256) void attn_weff_k(
    const float* __restrict__ part_qk, const float* __restrict__ part_sq_q,
    const float* __restrict__ part_sq_k, const float* __restrict__ proj_w,
    const float* __restrict__ temp, unsigned short* __restrict__ weff_s)
{
    __shared__ float at[32 * 33];
    __shared__ float nq[32], nk[32];
    int bh = blockIdx.x;
    int b = bh >> 3, h = bh & 7;
    int t = threadIdx.x;
    long pb0 = (long)bh * 8;
    float4 s = make_float4(0, 0, 0, 0);
    for (int c = 0; c < 8; ++c) {
        float4 v = *(const float4*)(part_qk + (pb0 + c) * 1024 + t * 4);
        s.x += v.x; s.y += v.y; s.z += v.z; s.w += v.w;
    }
    if (t < 32) {
        float a = 0;
        for (int c = 0; c < 8; ++c) a += part_sq_q[(pb0 + c) * 32 + t];
        nq[t] = fmaxf(sqrtf(a), 1e-12f);
    } else if (t < 64) {
        int j = t - 32;
        float a = 0;
        for (int c = 0; c < 8; ++c) a += part_sq_k[(pb0 + c) * 32 + j];
        nk[j] = fmaxf(sqrtf(a), 1e-12f);
    }
    __syncthreads();
    float tp = temp[h];
    int ci = t >> 3, cj0 = (t & 7) * 4;
    at[ci * 33 + cj0 + 0] = s.x / (nq[ci] * nk[cj0 + 0]) * tp;
    at[ci * 33 + cj0 + 1] = s.y / (nq[ci] * nk[cj0 + 1]) * tp;
    at[ci * 33 + cj0 + 2] = s.z / (nq[ci] * nk[cj0 + 2]) * tp;
    at[ci * 33 + cj0 + 3] = s.w / (nq[ci] * nk[cj0 + 3]) * tp;
    __syncthreads();
    if (t < 32) {
        float m = -1e30f;
        for (int j = 0; j < 32; ++j) m = fmaxf(m, at[t * 33 + j]);
        float ss = 0;
        for (int j = 0; j < 32; ++j) {
            float e = expf(at[t * 33 + j] - m);
            at[t * 33 + j] = e;
            ss += e;
        }
        float inv = 1.f / ss;
        for (int j = 0; j < 32; ++j) at[t * 33 + j] *= inv;
    }
    __syncthreads();
    int co = t;
    float pw[32];
#pragma unroll
    for (int i2 = 0; i2 < 32; ++i2) pw[i2] = proj_w[(long)co * CDIM + h * 32 + i2];
    unsigned short* wb = weff_s + (long)b * 65536 + (long)h * (256 * 32) + co * 32;
    int swz = (co >> 1) & 3;
    for (int j = 0; j < 32; ++j) {
        float a = 0;
#pragma unroll
        for (int i2 = 0; i2 < 32; ++i2) a = fmaf(pw[i2], at[i2 * 33 + j], a);
        wb[((j >> 3) ^ swz) * 8 + (j & 7)] = f2bf(a);
    }
}

// ---------------------------------------------------------------------------
extern "C" void kernel_launch(void* const* d_in, const int* in_sizes, int n_in,
                              void* d_out, int out_size, void* d_ws, size_t ws_size,
                              hipStream_t stream)
{
    const float* low    = (const float*)d_in[0];
    const float* high   = (const float*)d_in[1];
    const float* q_w    = (const float*)d_in[2];
    const float* q_dw   = (const float*)d_in[3];
    const float* kv_w   = (const float*)d_in[4];
    const float* kv_dw  = (const float*)d_in[5];
    const float* proj_w = (const float*)d_in[6];
    const float* temp   = (const float*)d_in[7];
    float* out = (float*)d_out;

    // workspace (bf16 elems)
    unsigned short* usws = (unsigned short*)d_ws;
    unsigned short* Areg = usws;                  // [4][512][HW]   8*SZB
    unsigned short* VT   = Areg + 8 * SZB;        // [4][8][HW][32] 4*SZB
    unsigned short* wkv_s = VT + 4 * SZB;         // [8][512][32]
    unsigned short* wq_s  = wkv_s + 131072;       // [8][256][32]
    unsigned short* weff_s = wq_s + 65536;        // [4][8][256][32]
    float* part_qk   = (float*)(weff_s + 4L * 65536);
    float* part_sq_q = part_qk + 32L * 8 * 1024;
    float* part_sq_k = part_sq_q + 32L * 8 * 32;
    float* endp      = part_sq_k + 32L * 8 * 32;
    if (ws_size < (size_t)((char*)endp - (char*)d_ws)) return;

    // d_out as scratch: K_all then Q_all (bf16), consumed before final write
    unsigned short* K_all = (unsigned short*)d_out;           // [4][256][HW]
    unsigned short* Q_all = K_all + 4 * SZB;                  // [4][256][HW]

    dim3 blk(256);

    // all weights -> swizzled bf16 (1 dispatch)
    cvtw_k<<<dim3(96), blk, 0, stream>>>(kv_w, q_w, wkv_s, wq_s);

    // kv chain: fused K+V GEMM straight from fp32 low
    gemm2_k<0, 1><<<dim3(4, 200, NB), blk, 0, stream>>>(
        low, wkv_s, Areg, SZB, 0, 2 * SZB, 512);
    dwK_k<<<dim3(20, 32, NB), blk, 0, stream>>>(Areg, kv_dw, K_all, 2 * SZB);
    dwV_k<<<dim3(40, 16, NB), blk, 0, stream>>>(Areg + 256L * HW,
                                                kv_dw + 256 * 9, VT, 2 * SZB);

    // q chain (reuses Areg rows 0..255, stride 2*SZB)
    gemm2_k<0, 1><<<dim3(2, 200, NB), blk, 0, stream>>>(
        high, wq_s, Areg, SZB, 0, 2 * SZB, 256);
    dwK_k<<<dim3(20, 32, NB), blk, 0, stream>>>(Areg, q_dw, Q_all, 2 * SZB);

    // gram + softmax + W_eff
    gram_k<<<dim3(8, NHEADS, NB), blk, 0, stream>>>(Q_all, K_all, part_qk,
                                                    part_sq_q, part_sq_k);
    attn_weff_k<<<dim3(32), blk, 0, stream>>>(
        part_qk, part_sq_q, part_sq_k, proj_w, temp, weff_s);

    // out[b] = W_eff[b] @ v[b]
    gemm2_k<1, 0><<<dim3(2, 200, NB), blk, 0, stream>>>(VT, weff_s, out,
                                                        SZB, 65536, SZB, 256);
}

// Round 11
// 288.743 us; speedup vs baseline: 1.1049x; 1.0674x over previous
//
#include <hip/hip_runtime.h>
#include <math.h>

#define HW 25600
#define IMGW 160
#define CDIM 256
#define NB 4
#define NHEADS 8
#define SZB ((long)CDIM * HW)   // 6,553,600 elems

typedef __attribute__((ext_vector_type(8))) short short8v;
typedef __attribute__((ext_vector_type(4))) float f32x4;
typedef __attribute__((ext_vector_type(8))) unsigned short us8;

union FragU {
    us8 o;
    short8v s;
    unsigned u32[4];
};

__device__ inline unsigned short f2bf(float f) {
    unsigned u = __float_as_uint(f);
    return (unsigned short)((u + 0x7fffu + ((u >> 16) & 1u)) >> 16);
}
__device__ inline float bf2f(unsigned short h) {
    return __uint_as_float(((unsigned)h) << 16);
}

// ---------------------------------------------------------------------------
// all weights fp32 -> swizzled bf16, one dispatch.
// kv_w [512][256] -> wkv_s [8kt][512][32]; q_w [256][256] -> wq_s [8kt][256][32]
// slot(g2, co) = g2 ^ ((co>>1)&3).  grid(96)
// ---------------------------------------------------------------------------
__global__ __launch_bounds__(256) void cvtw_k(
    const float* __restrict__ kv_w, const float* __restrict__ q_w,
    unsigned short* __restrict__ wkv_s, unsigned short* __restrict__ wq_s)
{
    int idx = blockIdx.x * 256 + threadIdx.x;   // 0..24575
    int g2 = idx & 3;
    int kt = (idx >> 2) & 7;
    int co = idx >> 5;                          // 0..767
    const float* src;
    unsigned short* dst;
    int nco, co_l;
    if (co < 512) { src = kv_w; dst = wkv_s; nco = 512; co_l = co; }
    else          { src = q_w;  dst = wq_s;  nco = 256; co_l = co - 512; }
    src += (long)co_l * CDIM + kt * 32 + g2 * 8;
    us8 v;
#pragma unroll
    for (int u = 0; u < 8; ++u) v[u] = f2bf(src[u]);
    int slot = g2 ^ ((co_l >> 1) & 3);
    *(us8*)(dst + ((long)kt * nco + co_l) * 32 + slot * 8) = v;
}

// ---------------------------------------------------------------------------
// bf16 MFMA GEMM v3: out[b][co][n] = sum_k W[co][k] * X[k][n]
// Double-buffered single-barrier K-loop (stage kt+1 BEFORE computing kt; the
// compiler's vmcnt(0)-before-barrier then lands after the MFMAs -> load
// latency hides under compute). Coalesced epilogue via LDS bounce.
// W in swizzled [kt][nco][32] bf16 (glds staged).
// XF32=1: X fp32 [k][HW]; reg loads + cvt_pk -> [128n][40] bf16 LDS tile.
// XF32=0: X swizzled bf16 [kt][HW][32] (glds staged, inverse-swz read).
// XCD-bijective block swizzle. Requires (gridDim.x*gridDim.y) % 8 == 0.
// ---------------------------------------------------------------------------
template<int OUTF32, int XF32>
__global__ __launch_bounds__(256) void gemm3_k(
    const void* __restrict__ Xv, const unsigned short* __restrict__ WS,
    void* __restrict__ outp, long xbs, long wbs, long obs, int nco)
{
    __shared__ __align__(16) char SMEM[36864];
    unsigned short* Wl = (unsigned short*)SMEM;             // 2 x 4096 elems
    unsigned short* Xl = (unsigned short*)(SMEM + 16384);   // 2 x (5120|4096)
    const int XST = XF32 ? 5120 : 4096;

    const int t  = threadIdx.x;
    const int l  = t & 63;
    const int wv = t >> 6;
    const int g  = l >> 4;
    const int ln = l & 15;

    // XCD-aware bijective swizzle (nwg % 8 == 0)
    const int NX = gridDim.x;
    const int orig = blockIdx.y * NX + blockIdx.x;
    const int chunkp = (NX * gridDim.y) >> 3;
    const int wgid = (orig & 7) * chunkp + (orig >> 3);
    const int co0 = (wgid % NX) * 128;
    const int n0  = (wgid / NX) * 128;

    const long b  = blockIdx.z;
    const unsigned short* Wb  = WS + b * wbs;
    const float* Xfp          = (const float*)Xv + b * xbs;
    const unsigned short* Xbf = (const unsigned short*)Xv + b * xbs;
    const int wr = wv >> 1, wc = wv & 1;

    f32x4 acc[4][4];
#pragma unroll
    for (int i = 0; i < 4; ++i)
#pragma unroll
        for (int j = 0; j < 4; ++j) acc[i][j] = (f32x4){0.f, 0.f, 0.f, 0.f};

    const int lrow = l >> 2;      // glds: lane covers row (instr*16 + lrow)
    const int lgrp = l & 3;       // 16B group
    const int n_l = t & 127;      // XF32 staging: n within tile
    const int sb  = (t >> 7) * 2; // XF32 staging: strip base (k-groups of 8)

    float f[16];

#define STAGE_W(ktv, buf)                                                     \
    {                                                                         \
        _Pragma("unroll")                                                     \
        for (int ii = 0; ii < 2; ++ii) {                                      \
            int instr = wv * 2 + ii;                                          \
            int row = instr * 16 + lrow;                                      \
            const unsigned short* wsrc =                                      \
                Wb + ((long)(ktv) * nco + co0 + row) * 32 + lgrp * 8;         \
            __builtin_amdgcn_global_load_lds(                                 \
                (const __attribute__((address_space(1))) void*)wsrc,          \
                (__attribute__((address_space(3))) void*)                     \
                    &Wl[(buf) * 4096 + instr * 512], 16, 0, 0);               \
        }                                                                     \
    }
#define STAGE_XG(ktv, buf)                                                    \
    {                                                                         \
        _Pragma("unroll")                                                     \
        for (int ii = 0; ii < 2; ++ii) {                                      \
            int instr = wv * 2 + ii;                                          \
            int row = instr * 16 + lrow;                                      \
            const unsigned short* xsrc =                                      \
                Xbf + ((long)(ktv) * HW + n0 + row) * 32 + lgrp * 8;          \
            __builtin_amdgcn_global_load_lds(                                 \
                (const __attribute__((address_space(1))) void*)xsrc,          \
                (__attribute__((address_space(3))) void*)                     \
                    &Xl[(buf) * 4096 + instr * 512], 16, 0, 0);               \
        }                                                                     \
    }
#define LOAD_XF(ktv)                                                          \
    {                                                                         \
        _Pragma("unroll")                                                     \
        for (int si = 0; si < 2; ++si)                                        \
            _Pragma("unroll")                                                 \
            for (int u = 0; u < 8; ++u)                                       \
                f[si * 8 + u] =                                               \
                    Xfp[(long)((ktv) * 32 + (sb + si) * 8 + u) * HW + n0 + n_l]; \
    }
#define WRITE_XF(buf)                                                         \
    {                                                                         \
        _Pragma("unroll")                                                     \
        for (int si = 0; si < 2; ++si) {                                      \
            FragU cv;                                                         \
            _Pragma("unroll")                                                 \
            for (int e2 = 0; e2 < 4; ++e2) {                                  \
                unsigned rr;                                                  \
                asm("v_cvt_pk_bf16_f32 %0, %1, %2"                            \
                    : "=v"(rr) : "v"(f[si * 8 + e2 * 2]),                     \
                      "v"(f[si * 8 + e2 * 2 + 1]));                           \
                cv.u32[e2] = rr;                                              \
            }                                                                 \
            *(us8*)&Xl[(buf) * XST + n_l * 40 + (sb + si) * 8] = cv.o;        \
        }                                                                     \
    }

    // prologue: stage kt=0 into buffer 0
    STAGE_W(0, 0);
    if (XF32) { LOAD_XF(0); WRITE_XF(0); }
    else      { STAGE_XG(0, 0); }
    __syncthreads();

    for (int kt = 0; kt < 8; ++kt) {
        const int cur = kt & 1, nxt = cur ^ 1;
        // issue next-tile staging FIRST (overlaps with compute below)
        if (kt < 7) {
            STAGE_W(kt + 1, nxt);
            if (XF32) { LOAD_XF(kt + 1); }
            else      { STAGE_XG(kt + 1, nxt); }
        }
        // compute current tile
        FragU A_[4], B_[4];
#pragma unroll
        for (int i = 0; i < 4; ++i) {
            int row = wr * 64 + i * 16 + ln;
            int slot = g ^ ((row >> 1) & 3);
            A_[i].o = *(const us8*)&Wl[cur * 4096 + row * 32 + slot * 8];
        }
        if (XF32) {
#pragma unroll
            for (int j = 0; j < 4; ++j) {
                int row = wc * 64 + j * 16 + ln;
                B_[j].o = *(const us8*)&Xl[cur * XST + row * 40 + g * 8];
            }
        } else {
#pragma unroll
            for (int j = 0; j < 4; ++j) {
                int row = wc * 64 + j * 16 + ln;
                int slot = g ^ ((row >> 1) & 3);
                B_[j].o = *(const us8*)&Xl[cur * XST + row * 32 + slot * 8];
            }
        }
#pragma unroll
        for (int i = 0; i < 4; ++i)
#pragma unroll
            for (int j = 0; j < 4; ++j)
                acc[i][j] = __builtin_amdgcn_mfma_f32_16x16x32_bf16(
                    A_[i].s, B_[j].s, acc[i][j], 0, 0, 0);
        // late write of prefetched X (waits only on the reg loads)
        if (kt < 7 && XF32) { WRITE_XF(nxt); }
        __syncthreads();
    }
#undef STAGE_W
#undef STAGE_XG
#undef LOAD_XF
#undef WRITE_XF

    // ---- coalesced epilogue via LDS bounce (SMEM reuse safe: barrier above)
    if (OUTF32) {
        float* ef = (float*)SMEM;   // [64][132] fp32, 33792 B
        float* ob = (float*)outp + b * obs;
#pragma unroll
        for (int h2 = 0; h2 < 2; ++h2) {
            if (wr == h2) {
#pragma unroll
                for (int i = 0; i < 4; ++i)
#pragma unroll
                    for (int j = 0; j < 4; ++j)
#pragma unroll
                        for (int r = 0; r < 4; ++r)
                            ef[(i * 16 + g * 4 + r) * 132 + wc * 64 + j * 16 + ln]
                                = acc[i][j][r];
            }
            __syncthreads();
#pragma unroll
            for (int p = 0; p < 8; ++p) {
                int idx = p * 256 + t;         // 2048 float4 chunks
                int row = idx >> 5;
                int c4 = (idx & 31) * 4;
                float4 v = *(const float4*)&ef[row * 132 + c4];
                *(float4*)(ob + (long)(co0 + h2 * 64 + row) * HW + n0 + c4) = v;
            }
            __syncthreads();
        }
    } else {
        unsigned short* eb = (unsigned short*)SMEM;  // [128][136] bf16, 34816 B
        unsigned short* ob = (unsigned short*)outp + b * obs;
#pragma unroll
        for (int i = 0; i < 4; ++i)
#pragma unroll
            for (int j = 0; j < 4; ++j)
#pragma unroll
                for (int r = 0; r < 4; ++r)
                    eb[(wr * 64 + i * 16 + g * 4 + r) * 136 + wc * 64 + j * 16 + ln]
                        = f2bf(acc[i][j][r]);
        __syncthreads();
#pragma unroll
        for (int p = 0; p < 8; ++p) {
            int idx = p * 256 + t;              // 2048 us8 chunks
            int row = idx >> 4;
            int c8 = (idx & 15) * 8;
            us8 v = *(const us8*)&eb[row * 136 + c8];
            *(us8*)(ob + (long)(co0 + row) * HW + n0 + c8) = v;
        }
    }
}

// ---------------------------------------------------------------------------
// depthwise 3x3 bf16, normal output [c][HW].
// Tile: 8 output rows x 160 px x 8 ch. Halo 10/8 rows = 1.25x fetch.
// grid (20, 32, NB). bstride = input batch stride (elems).
// ---------------------------------------------------------------------------
__global__ __launch_bounds__(256) void dwK_k(
    const unsigned short* __restrict__ A, const float* __restrict__ w,
    unsigned short* __restrict__ out, long bstride)
{
    __shared__ unsigned short xsh[8][10][168];
    const int t = threadIdx.x;
    const int y0 = blockIdx.x * 8;
    const int c0 = blockIdx.y * 8;
    const long b = blockIdx.z;
    const unsigned short* Ab = A + b * bstride;

    for (int idx = t; idx < 1600; idx += 256) {
        int seg = idx % 20;
        int row = (idx / 20) % 10;
        int ch  = idx / 200;
        int yy  = y0 + row - 1;
        us8 v = (us8){0, 0, 0, 0, 0, 0, 0, 0};
        if (yy >= 0 && yy < IMGW)
            v = *(const us8*)(Ab + (long)(c0 + ch) * HW + yy * IMGW + seg * 8);
        *(us8*)&xsh[ch][row][seg * 8] = v;
    }
    __syncthreads();

    const int ch = t >> 5;
    const int rem = t & 31;
    const int ro = rem >> 2;
    const int xq = rem & 3;
    float wreg[9];
#pragma unroll
    for (int u = 0; u < 9; ++u) wreg[u] = w[(c0 + ch) * 9 + u];
    unsigned short* ob = out + b * SZB + (long)(c0 + ch) * HW + (y0 + ro) * IMGW;

#pragma unroll
    for (int xs = 0; xs < 5; ++xs) {
        int x = xq * 8 + xs * 32;
        float s[8];
#pragma unroll
        for (int p = 0; p < 8; ++p) s[p] = 0.f;
#pragma unroll
        for (int dy = 0; dy < 3; ++dy) {
            const unsigned short* rp = &xsh[ch][ro + dy][0];
            float r[10];
            r[0] = (x > 0) ? bf2f(rp[x - 1]) : 0.f;
            us8 mid = *(const us8*)&rp[x];
#pragma unroll
            for (int u = 0; u < 8; ++u) r[1 + u] = bf2f(mid[u]);
            r[9] = (x + 8 < IMGW) ? bf2f(rp[x + 8]) : 0.f;
            float w0 = wreg[dy * 3], w1 = wreg[dy * 3 + 1], w2 = wreg[dy * 3 + 2];
#pragma unroll
            for (int p = 0; p < 8; ++p)
                s[p] = fmaf(w0, r[p], fmaf(w1, r[p + 1], fmaf(w2, r[p + 2], s[p])));
        }
        us8 o;
#pragma unroll
        for (int p = 0; p < 8; ++p) o[p] = f2bf(s[p]);
        *(us8*)(ob + x) = o;
    }
}

// ---------------------------------------------------------------------------
// depthwise 3x3 bf16, transposed+swizzled output [kt][HW][32] (for V).
// Tile: 4 output rows x 160 px x 16 ch. grid (40, 16, NB).
// ---------------------------------------------------------------------------
__global__ __launch_bounds__(256) void dwV_k(
    const unsigned short* __restrict__ A, const float* __restrict__ w,
    unsigned short* __restrict__ out, long bstride)
{
    __shared__ unsigned short xsh[16][6][168];
    __shared__ unsigned short osh[640][17];
    const int t = threadIdx.x;
    const int y0 = blockIdx.x * 4;
    const int c0 = blockIdx.y * 16;
    const long b = blockIdx.z;
    const unsigned short* Ab = A + b * bstride;

    for (int idx = t; idx < 1920; idx += 256) {
        int seg = idx % 20;
        int row = (idx / 20) % 6;
        int ch  = idx / 120;
        int yy  = y0 + row - 1;
        us8 v = (us8){0, 0, 0, 0, 0, 0, 0, 0};
        if (yy >= 0 && yy < IMGW)
            v = *(const us8*)(Ab + (long)(c0 + ch) * HW + yy * IMGW + seg * 8);
        *(us8*)&xsh[ch][row][seg * 8] = v;
    }
    __syncthreads();

    {
        const int ch = t >> 4;
        const int rem = t & 15;
        const int ro = rem >> 2;
        const int xq = rem & 3;
        float wreg[9];
#pragma unroll
        for (int u = 0; u < 9; ++u) wreg[u] = w[(c0 + ch) * 9 + u];
#pragma unroll
        for (int xs = 0; xs < 5; ++xs) {
            int x = xq * 8 + xs * 32;
            float s[8];
#pragma unroll
            for (int p = 0; p < 8; ++p) s[p] = 0.f;
#pragma unroll
            for (int dy = 0; dy < 3; ++dy) {
                const unsigned short* rp = &xsh[ch][ro + dy][0];
                float r[10];
                r[0] = (x > 0) ? bf2f(rp[x - 1]) : 0.f;
                us8 mid = *(const us8*)&rp[x];
#pragma unroll
                for (int u = 0; u < 8; ++u) r[1 + u] = bf2f(mid[u]);
                r[9] = (x + 8 < IMGW) ? bf2f(rp[x + 8]) : 0.f;
                float w0 = wreg[dy * 3], w1 = wreg[dy * 3 + 1], w2 = wreg[dy * 3 + 2];
#pragma unroll
                for (int p = 0; p < 8; ++p)
                    s[p] = fmaf(w0, r[p], fmaf(w1, r[p + 1], fmaf(w2, r[p + 2], s[p])));
            }
            int nl = ro * IMGW + x;
#pragma unroll
            for (int p = 0; p < 8; ++p) osh[nl + p][ch] = f2bf(s[p]);
        }
    }
    __syncthreads();

    for (int idx = t; idx < 1280; idx += 256) {
        int nl = idx >> 1;
        int c8 = (idx & 1) * 8;
        us8 o;
#pragma unroll
        for (int u = 0; u < 8; ++u) o[u] = osh[nl][c8 + u];
        int n  = y0 * IMGW + nl;
        int cg = c0 + c8;
        int kt = cg >> 5;
        int g2 = (cg >> 3) & 3;
        int slot = g2 ^ ((n >> 1) & 3);
        *(us8*)(out + b * SZB + ((long)kt * HW + n) * 32 + slot * 8) = o;
    }
}

// ---------------------------------------------------------------------------
// gram via MFMA, direct global us8 frag loads (same k-slot map both operands).
// grid (8 chunks, 8 heads, NB)
// ---------------------------------------------------------------------------
__global__ __launch_bounds__(256) void gram_k(
    const unsigned short* __restrict__ q, const unsigned short* __restrict__ k,
    float* __restrict__ part_qk, float* __restrict__ part_sq_q,
    float* __restrict__ part_sq_k)
{
    __shared__ float Sred[4 * 1024];
    __shared__ float sqq_l[4][32];
    __shared__ float sqk_l[4][32];
    const int t  = threadIdx.x;
    const int l  = t & 63;
    const int wv = t >> 6;
    const int g  = l >> 4;
    const int ln = l & 15;
    const int chunk = blockIdx.x;
    const int h = blockIdx.y;
    const int b = blockIdx.z;

    f32x4 accS[2][2], accQ[2], accK[2];
#pragma unroll
    for (int i = 0; i < 2; ++i) {
        accQ[i] = (f32x4){0, 0, 0, 0};
        accK[i] = (f32x4){0, 0, 0, 0};
#pragma unroll
        for (int j = 0; j < 2; ++j) accS[i][j] = (f32x4){0, 0, 0, 0};
    }

    const unsigned short* qb = q + (long)b * SZB + (long)(h * 32) * HW;
    const unsigned short* kb = k + (long)b * SZB + (long)(h * 32) * HW;
    long nb = (long)chunk * 3200 + wv * 800;
    for (int s = 0; s < 25; ++s, nb += 32) {
        FragU aq[2], bk[2];
#pragma unroll
        for (int i = 0; i < 2; ++i)
            aq[i].o = *(const us8*)(qb + (long)(i * 16 + ln) * HW + nb + g * 8);
#pragma unroll
        for (int j = 0; j < 2; ++j)
            bk[j].o = *(const us8*)(kb + (long)(j * 16 + ln) * HW + nb + g * 8);
#pragma unroll
        for (int i = 0; i < 2; ++i)
#pragma unroll
            for (int j = 0; j < 2; ++j)
                accS[i][j] = __builtin_amdgcn_mfma_f32_16x16x32_bf16(
                    aq[i].s, bk[j].s, accS[i][j], 0, 0, 0);
#pragma unroll
        for (int i = 0; i < 2; ++i) {
            accQ[i] = __builtin_amdgcn_mfma_f32_16x16x32_bf16(
                aq[i].s, aq[i].s, accQ[i], 0, 0, 0);
            accK[i] = __builtin_amdgcn_mfma_f32_16x16x32_bf16(
                bk[i].s, bk[i].s, accK[i], 0, 0, 0);
        }
    }
#pragma unroll
    for (int i = 0; i < 2; ++i)
#pragma unroll
        for (int j = 0; j < 2; ++j)
#pragma unroll
            for (int r = 0; r < 4; ++r) {
                int row = i * 16 + g * 4 + r;
                int col = j * 16 + ln;
                Sred[wv * 1024 + row * 32 + col] = accS[i][j][r];
            }
#pragma unroll
    for (int i = 0; i < 2; ++i)
#pragma unroll
        for (int r = 0; r < 4; ++r)
            if (ln == g * 4 + r) {
                sqq_l[wv][i * 16 + g * 4 + r] = accQ[i][r];
                sqk_l[wv][i * 16 + g * 4 + r] = accK[i][r];
            }
    __syncthreads();
    const long pb = ((long)(b * NHEADS + h) * 8 + chunk);
#pragma unroll
    for (int e0 = 0; e0 < 4; ++e0) {
        int e = e0 * 256 + t;
        float v = Sred[e] + Sred[1024 + e] + Sred[2048 + e] + Sred[3072 + e];
        part_qk[pb * 1024 + e] = v;
    }
    if (t < 32)
        part_sq_q[pb * 32 + t] = sqq_l[0][t] + sqq_l[1][t] + sqq_l[2][t] + sqq_l[3][t];
    else if (t < 64) {
        int j = t - 32;
        part_sq_k[pb * 32 + j] = sqk_l[0][j] + sqk_l[1][j] + sqk_l[2][j] + sqk_l[3][j];
    }
}

// ---------------------------------------------------------------------------
// reduce -> normalize -> softmax -> W_eff = proj_w @ blockdiag(attn),
// stored in swizzled [b][kt=h][256][32] layout. grid 32 = (b,h)
// ---------------------------------------------------------------------------
__global__ __launch_bounds__(256) void attn_weff_k(
    const float* __restrict__ part_qk, const float* __restrict__ part_sq_q,
    const float* __restrict__ part_sq_k, const float* __restrict__ proj_w,
    const float* __restrict__ temp, unsigned short* __restrict__ weff_s)
{
    __shared__ float at[32 * 33];
    __shared__ float nq[32], nk[32];
    int bh = blockIdx.x;
    int b = bh >> 3, h = bh & 7;
    int t = threadIdx.x;
    long pb0 = (long)bh * 8;
    float4 s = make_float4(0, 0, 0, 0);
    for (int c = 0; c < 8; ++c) {
        float4 v = *(const float4*)(part_qk + (pb0 + c) * 1024 + t * 4);
        s.x += v.x; s.y += v.y; s.z += v.z; s.w += v.w;
    }
    if (t < 32) {
        float a = 0;
        for (int c = 0; c < 8; ++c) a += part_sq_q[(pb0 + c) * 32 + t];
        nq[t] = fmaxf(sqrtf(a), 1e-12f);
    } else if (t < 64) {
        int j = t - 32;
        float a = 0;
        for (int c = 0; c < 8; ++c) a += part_sq_k[(pb0 + c) * 32 + j];
        nk[j] = fmaxf(sqrtf(a), 1e-12f);
    }
    __syncthreads();
    float tp = temp[h];
    int ci = t >> 3, cj0 = (t & 7) * 4;
    at[ci * 33 + cj0 + 0] = s.x / (nq[ci] * nk[cj0 + 0]) * tp;
    at[ci * 33 + cj0 + 1] = s.y / (nq[ci] * nk[cj0 + 1]) * tp;
    at[ci * 33 + cj0 + 2] = s.z / (nq[ci] * nk[cj0 + 2]) * tp;
    at[ci * 33 + cj0 + 3] = s.w / (nq[ci] * nk[cj0 + 3]) * tp;
    __syncthreads();
    if (t < 32) {
        float m = -1e30f;
        for (int j = 0; j < 32; ++j) m = fmaxf(m, at[t * 33 + j]);
        float ss = 0;
        for (int j = 0; j < 32; ++j) {
            float e = expf(at[t * 33 + j] - m);
            at[t * 33 + j] = e;
            ss += e;
        }
        float inv = 1.f / ss;
        for (int j = 0; j < 32; ++j) at[t * 33 + j] *= inv;
    }
    __syncthreads();
    int co = t;
    float pw[32];
#pragma unroll
    for (int i2 = 0; i2 < 32; ++i2) pw[i2] = proj_w[(long)co * CDIM + h * 32 + i2];
    unsigned short* wb = weff_s + (long)b * 65536 + (long)h * (256 * 32) + co * 32;
    int swz = (co >> 1) & 3;
    for (int j = 0; j < 32; ++j) {
        float a = 0;
#pragma unroll
        for (int i2 = 0; i2 < 32; ++i2) a = fmaf(pw[i2], at[i2 * 33 + j], a);
        wb[((j >> 3) ^ swz) * 8 + (j & 7)] = f2bf(a);
    }
}

// ---------------------------------------------------------------------------
extern "C" void kernel_launch(void* const* d_in, const int* in_sizes, int n_in,
                              void* d_out, int out_size, void* d_ws, size_t ws_size,
                              hipStream_t stream)
{
    const float* low    = (const float*)d_in[0];
    const float* high   = (const float*)d_in[1];
    const float* q_w    = (const float*)d_in[2];
    const float* q_dw   = (const float*)d_in[3];
    const float* kv_w   = (const float*)d_in[4];
    const float* kv_dw  = (const float*)d_in[5];
    const float* proj_w = (const float*)d_in[6];
    const float* temp   = (const float*)d_in[7];
    float* out = (float*)d_out;

    // workspace (bf16 elems)
    unsigned short* usws = (unsigned short*)d_ws;
    unsigned short* Areg = usws;                  // [4][512][HW]   8*SZB
    unsigned short* VT   = Areg + 8 * SZB;        // [4][8][HW][32] 4*SZB
    unsigned short* wkv_s = VT + 4 * SZB;         // [8][512][32]
    unsigned short* wq_s  = wkv_s + 131072;       // [8][256][32]
    unsigned short* weff_s = wq_s + 65536;        // [4][8][256][32]
    float* part_qk   = (float*)(weff_s + 4L * 65536);
    float* part_sq_q = part_qk + 32L * 8 * 1024;
    float* part_sq_k = part_sq_q + 32L * 8 * 32;
    float* endp      = part_sq_k + 32L * 8 * 32;
    if (ws_size < (size_t)((char*)endp - (char*)d_ws)) return;

    // d_out as scratch: K_all then Q_all (bf16), consumed before final write
    unsigned short* K_all = (unsigned short*)d_out;           // [4][256][HW]
    unsigned short* Q_all = K_all + 4 * SZB;                  // [4][256][HW]

    dim3 blk(256);

    // all weights -> swizzled bf16 (1 dispatch)
    cvtw_k<<<dim3(96), blk, 0, stream>>>(kv_w, q_w, wkv_s, wq_s);

    // kv chain: fused K+V GEMM straight from fp32 low
    gemm3_k<0, 1><<<dim3(4, 200, NB), blk, 0, stream>>>(
        low, wkv_s, Areg, SZB, 0, 2 * SZB, 512);
    dwK_k<<<dim3(20, 32, NB), blk, 0, stream>>>(Areg, kv_dw, K_all, 2 * SZB);
    dwV_k<<<dim3(40, 16, NB), blk, 0, stream>>>(Areg + 256L * HW,
                                                kv_dw + 256 * 9, VT, 2 * SZB);

    // q chain (reuses Areg rows 0..255, stride 2*SZB)
    gemm3_k<0, 1><<<dim3(2, 200, NB), blk, 0, stream>>>(
        high, wq_s, Areg, SZB, 0, 2 * SZB, 256);
    dwK_k<<<dim3(20, 32, NB), blk, 0, stream>>>(Areg, q_dw, Q_all, 2 * SZB);

    // gram + softmax + W_eff
    gram_k<<<dim3(8, NHEADS, NB), blk, 0, stream>>>(Q_all, K_all, part_qk,
                                                    part_sq_q, part_sq_k);
    attn_weff_k<<<dim3(32), blk, 0, stream>>>(
        part_qk, part_sq_q, part_sq_k, proj_w, temp, weff_s);

    // out[b] = W_eff[b] @ v[b]
    gemm3_k<1, 0><<<dim3(2, 200, NB), blk, 0, stream>>>(VT, weff_s, out,
                                                        SZB, 65536, SZB, 256);
}